// Round 2
// baseline (1165.895 us; speedup 1.0000x reference)
//
#include <hip/hip_runtime.h>

typedef short short8 __attribute__((ext_vector_type(8)));
typedef float f32x4  __attribute__((ext_vector_type(4)));

#define NFQ 128
#define CH  256

__device__ __forceinline__ unsigned short f2bf(float f) {
  unsigned u = __float_as_uint(f);
  u += 0x7fffu + ((u >> 16) & 1u);
  return (unsigned short)(u >> 16);
}
__device__ __forceinline__ float bf2f(unsigned short h) {
  return __uint_as_float(((unsigned)h) << 16);
}

// prep: wf = bf16(Wg*Wv) [256][256], bfull = Wg*bv + bg (f32), biasf = alpha*relu(adj) (f32),
//       wqb/wkb = bf16(Wq/Wk)
__global__ void akg_prep(const float* __restrict__ Wg,
                         const float* __restrict__ Wv,
                         const float* __restrict__ bv,
                         const float* __restrict__ bg,
                         const float* __restrict__ adj,
                         const float* __restrict__ alpha,
                         const float* __restrict__ Wq,
                         const float* __restrict__ Wk,
                         unsigned short* __restrict__ wf,
                         float* __restrict__ bfull,
                         float* __restrict__ biasf,
                         unsigned short* __restrict__ wqb,
                         unsigned short* __restrict__ wkb) {
  int blk = blockIdx.x, t = threadIdx.x;
  if (blk < 256) {
    float acc = 0.f;
#pragma unroll 8
    for (int j = 0; j < 256; j++)
      acc += Wg[blk*256 + j] * Wv[j*256 + t];   // wf[c][k] = sum_j Wg[c][j] Wv[j][k]
    wf[blk*256 + t] = f2bf(acc);
  } else if (blk == 256) {
    float acc = bg[t];
#pragma unroll 8
    for (int j = 0; j < 256; j++)
      acc += Wg[t*256 + j] * bv[j];
    bfull[t] = acc;
  } else if (blk == 257) {
    float a = alpha[0];
    for (int i = t; i < 128*128; i += 256)
      biasf[i] = a * fmaxf(adj[i], 0.f);
  } else if (blk == 258) {
    for (int i = t; i < 128*256; i += 256) wqb[i] = f2bf(Wq[i]);
  } else {
    for (int i = t; i < 128*256; i += 256) wkb[i] = f2bf(Wk[i]);
  }
}

// LDS = 69,632 B -> 2 blocks/CU. QK first; VW in two 128-col halves after attention,
// each half reusing the dead K region. z-halves packed to bf16 immediately after their
// MFMA so worst-case VGPR live set stays well under the 128-reg cap (no spills).
__global__ __launch_bounds__(512, 4) void akg_main(
    const float* __restrict__ x,
    const float* __restrict__ ent,
    const unsigned short* __restrict__ wqb,
    const float* __restrict__ bq,
    const unsigned short* __restrict__ wkb,
    const float* __restrict__ bk,
    const unsigned short* __restrict__ wf,
    const float* __restrict__ bfull,
    const float* __restrict__ biasf,
    const float* __restrict__ gma,
    const float* __restrict__ bta,
    float* __restrict__ out) {
  const int b    = blockIdx.x;
  const int t    = threadIdx.x;
  const int wv   = t >> 6;          // wave 0..7, owns rows [16wv, 16wv+16)
  const int lane = t & 63;
  const int q    = lane >> 4;       // quad
  const int l16  = lane & 15;
  const int rw   = wv * 16;

  __shared__ __align__(16) unsigned short S[34816];   // 69,632 B -> 2 blocks/CU
  unsigned short* Qs = S;           // [128][136] bf16: Q', then attn (wave-private rows)
  unsigned short* Ks = S + 17408;   // [128][136] bf16: K, then VW^T half (128 cols)
  unsigned short* Hs = S;           // [128][264] bf16 relu(y) — reuses Qs+Ks after barrier

  const float* xb = x + (size_t)b * NFQ * CH;
  const int arow = rw + l16;
  const f32x4 zero4 = {0.f, 0.f, 0.f, 0.f};

  // ---- xe = x + ent A-fragments (bf16) for my 16 rows ----
  short8 xf[8];
#pragma unroll
  for (int ks = 0; ks < 8; ks++) {
    f32x4 a0 = *(const f32x4*)(xb + arow*CH + ks*32 + q*8);
    f32x4 a1 = *(const f32x4*)(xb + arow*CH + ks*32 + q*8 + 4);
    f32x4 e0 = *(const f32x4*)(ent + arow*CH + ks*32 + q*8);
    f32x4 e1 = *(const f32x4*)(ent + arow*CH + ks*32 + q*8 + 4);
    short8 s;
#pragma unroll
    for (int j = 0; j < 4; j++) {
      s[j]     = (short)f2bf(a0[j] + e0[j]);
      s[4 + j] = (short)f2bf(a1[j] + e1[j]);
    }
    xf[ks] = s;
  }

  // ---- K = xe*Wk^T + bk -> Ks ----
  f32x4 ac[8];
#pragma unroll
  for (int nt = 0; nt < 8; nt++) ac[nt] = zero4;
#pragma unroll
  for (int ks = 0; ks < 8; ks++) {
#pragma unroll
    for (int nt = 0; nt < 8; nt++) {
      short8 bf = *(const short8*)(wkb + (nt*16 + l16)*CH + ks*32 + q*8);
      ac[nt] = __builtin_amdgcn_mfma_f32_16x16x32_bf16(xf[ks], bf, ac[nt], 0, 0, 0);
    }
  }
#pragma unroll
  for (int nt = 0; nt < 8; nt++) {
    float bb = bk[nt*16 + l16];
#pragma unroll
    for (int r = 0; r < 4; r++)
      Ks[(rw + q*4 + r)*136 + nt*16 + l16] = f2bf(ac[nt][r] + bb);
  }

  // ---- Q' = (xe*Wq^T + bq)/sqrt(128) -> Qs ----
#pragma unroll
  for (int nt = 0; nt < 8; nt++) ac[nt] = zero4;
#pragma unroll
  for (int ks = 0; ks < 8; ks++) {
#pragma unroll
    for (int nt = 0; nt < 8; nt++) {
      short8 bf = *(const short8*)(wqb + (nt*16 + l16)*CH + ks*32 + q*8);
      ac[nt] = __builtin_amdgcn_mfma_f32_16x16x32_bf16(xf[ks], bf, ac[nt], 0, 0, 0);
    }
  }
  const float RS = 0.08838834764831845f;  // 1/sqrt(128)
#pragma unroll
  for (int nt = 0; nt < 8; nt++) {
    float bb = bq[nt*16 + l16];
#pragma unroll
    for (int r = 0; r < 4; r++)
      Qs[(rw + q*4 + r)*136 + nt*16 + l16] = f2bf((ac[nt][r] + bb) * RS);
  }

  __syncthreads();   // barrier1: Ks/Qs visible to all waves

  // ---- scores = Q'*K^T + bias ----
#pragma unroll
  for (int nt = 0; nt < 8; nt++) ac[nt] = zero4;
#pragma unroll
  for (int ks = 0; ks < 4; ks++) {
    short8 af = *(const short8*)(Qs + (rw + l16)*136 + ks*32 + q*8);
#pragma unroll
    for (int nt = 0; nt < 8; nt++) {
      short8 bf = *(const short8*)(Ks + (nt*16 + l16)*136 + ks*32 + q*8);
      ac[nt] = __builtin_amdgcn_mfma_f32_16x16x32_bf16(af, bf, ac[nt], 0, 0, 0);
    }
  }
#pragma unroll
  for (int nt = 0; nt < 8; nt++)
#pragma unroll
    for (int r = 0; r < 4; r++)
      ac[nt][r] += biasf[(rw + q*4 + r)*128 + nt*16 + l16];

  // ---- softmax per row (row = rw+q*4+r; cols spread over 16 lanes x 8 tiles) ----
  float inv[4];
#pragma unroll
  for (int r = 0; r < 4; r++) {
    float mx = -1e30f;
#pragma unroll
    for (int nt = 0; nt < 8; nt++) mx = fmaxf(mx, ac[nt][r]);
    mx = fmaxf(mx, __shfl_xor(mx, 1));
    mx = fmaxf(mx, __shfl_xor(mx, 2));
    mx = fmaxf(mx, __shfl_xor(mx, 4));
    mx = fmaxf(mx, __shfl_xor(mx, 8));
    float s = 0.f;
#pragma unroll
    for (int nt = 0; nt < 8; nt++) {
      float e = __expf(ac[nt][r] - mx);
      ac[nt][r] = e; s += e;
    }
    s += __shfl_xor(s, 1);
    s += __shfl_xor(s, 2);
    s += __shfl_xor(s, 4);
    s += __shfl_xor(s, 8);
    inv[r] = 1.f / s;
  }
  // attn -> Qs (own rows only; per-wave in-order DS makes write-then-read safe)
#pragma unroll
  for (int nt = 0; nt < 8; nt++)
#pragma unroll
    for (int r = 0; r < 4; r++)
      Qs[(rw + q*4 + r)*136 + nt*16 + l16] = f2bf(ac[nt][r] * inv[r]);

  // ---- reload x A-fragments (pure bf16(x) for VW halves; L2-hot) ----
#pragma unroll
  for (int ks = 0; ks < 8; ks++) {
    f32x4 a0 = *(const f32x4*)(xb + arow*CH + ks*32 + q*8);
    f32x4 a1 = *(const f32x4*)(xb + arow*CH + ks*32 + q*8 + 4);
    short8 s;
#pragma unroll
    for (int j = 0; j < 4; j++) {
      s[j]     = (short)f2bf(a0[j]);
      s[4 + j] = (short)f2bf(a1[j]);
    }
    xf[ks] = s;
  }

  __syncthreads();   // barrier2: scores-phase reads of Ks done -> safe to overwrite

  uint2 h1[8], h2[8];   // packed bf16 relu(z) halves (rows rw+q*4+{0..3} x col nt*16+l16)

  // ---- VW half 1 (cols 0..127) = x * wf^T (+bfull) -> Ks region, transposed ----
  {
    f32x4 vc[8];
#pragma unroll
    for (int nt = 0; nt < 8; nt++) vc[nt] = zero4;
#pragma unroll
    for (int ks = 0; ks < 8; ks++) {
#pragma unroll
      for (int nt = 0; nt < 8; nt++) {
        short8 bf = *(const short8*)(wf + (nt*16 + l16)*CH + ks*32 + q*8);
        vc[nt] = __builtin_amdgcn_mfma_f32_16x16x32_bf16(xf[ks], bf, vc[nt], 0, 0, 0);
      }
    }
#pragma unroll
    for (int nt = 0; nt < 8; nt++) {
      float bfc = bfull[nt*16 + l16];
      unsigned p0 = (unsigned)f2bf(vc[nt][0] + bfc) | ((unsigned)f2bf(vc[nt][1] + bfc) << 16);
      unsigned p1 = (unsigned)f2bf(vc[nt][2] + bfc) | ((unsigned)f2bf(vc[nt][3] + bfc) << 16);
      uint2 pk; pk.x = p0; pk.y = p1;
      *(uint2*)(Ks + (nt*16 + l16)*136 + rw + q*4) = pk;
    }
  }
  __syncthreads();   // barrier3: Vt half 1 visible

  // ---- z half 1 = attn * VW[:,0:128]; pack relu(z) immediately ----
  {
    f32x4 av[8];
#pragma unroll
    for (int nt = 0; nt < 8; nt++) av[nt] = zero4;
#pragma unroll
    for (int ks = 0; ks < 4; ks++) {
      short8 af = *(const short8*)(Qs + (rw + l16)*136 + ks*32 + q*8);
#pragma unroll
      for (int nt = 0; nt < 8; nt++) {
        short8 bf = *(const short8*)(Ks + (nt*16 + l16)*136 + ks*32 + q*8);
        av[nt] = __builtin_amdgcn_mfma_f32_16x16x32_bf16(af, bf, av[nt], 0, 0, 0);
      }
    }
#pragma unroll
    for (int nt = 0; nt < 8; nt++) {
      h1[nt].x = (unsigned)f2bf(fmaxf(av[nt][0], 0.f)) |
                 ((unsigned)f2bf(fmaxf(av[nt][1], 0.f)) << 16);
      h1[nt].y = (unsigned)f2bf(fmaxf(av[nt][2], 0.f)) |
                 ((unsigned)f2bf(fmaxf(av[nt][3], 0.f)) << 16);
    }
  }
  __syncthreads();   // barrier4: z-h1 reads done -> safe to overwrite Vt half

  // ---- VW half 2 (cols 128..255) -> Ks region ----
  {
    f32x4 vc[8];
#pragma unroll
    for (int nt = 0; nt < 8; nt++) vc[nt] = zero4;
#pragma unroll
    for (int ks = 0; ks < 8; ks++) {
#pragma unroll
      for (int nt = 0; nt < 8; nt++) {
        short8 bf = *(const short8*)(wf + ((nt + 8)*16 + l16)*CH + ks*32 + q*8);
        vc[nt] = __builtin_amdgcn_mfma_f32_16x16x32_bf16(xf[ks], bf, vc[nt], 0, 0, 0);
      }
    }
#pragma unroll
    for (int nt = 0; nt < 8; nt++) {
      float bfc = bfull[(nt + 8)*16 + l16];
      unsigned p0 = (unsigned)f2bf(vc[nt][0] + bfc) | ((unsigned)f2bf(vc[nt][1] + bfc) << 16);
      unsigned p1 = (unsigned)f2bf(vc[nt][2] + bfc) | ((unsigned)f2bf(vc[nt][3] + bfc) << 16);
      uint2 pk; pk.x = p0; pk.y = p1;
      *(uint2*)(Ks + (nt*16 + l16)*136 + rw + q*4) = pk;
    }
  }
  __syncthreads();   // barrier5: Vt half 2 visible

  // ---- z half 2 = attn * VW[:,128:256]; pack relu(z) immediately ----
  {
    f32x4 av[8];
#pragma unroll
    for (int nt = 0; nt < 8; nt++) av[nt] = zero4;
#pragma unroll
    for (int ks = 0; ks < 4; ks++) {
      short8 af = *(const short8*)(Qs + (rw + l16)*136 + ks*32 + q*8);
#pragma unroll
      for (int nt = 0; nt < 8; nt++) {
        short8 bf = *(const short8*)(Ks + (nt*16 + l16)*136 + ks*32 + q*8);
        av[nt] = __builtin_amdgcn_mfma_f32_16x16x32_bf16(af, bf, av[nt], 0, 0, 0);
      }
    }
#pragma unroll
    for (int nt = 0; nt < 8; nt++) {
      h2[nt].x = (unsigned)f2bf(fmaxf(av[nt][0], 0.f)) |
                 ((unsigned)f2bf(fmaxf(av[nt][1], 0.f)) << 16);
      h2[nt].y = (unsigned)f2bf(fmaxf(av[nt][2], 0.f)) |
                 ((unsigned)f2bf(fmaxf(av[nt][3], 0.f)) << 16);
    }
  }

  __syncthreads();   // barrier6: all reads of Qs(attn)/Ks(Vt) done -> overwrite with Hs

  // ---- relu(y) -> Hs (unpack packed halves) ----
#pragma unroll
  for (int nt = 0; nt < 8; nt++) {
    const int col = nt*16 + l16;
    Hs[(rw + q*4 + 0)*264 + col] = (unsigned short)(h1[nt].x & 0xffffu);
    Hs[(rw + q*4 + 1)*264 + col] = (unsigned short)(h1[nt].x >> 16);
    Hs[(rw + q*4 + 2)*264 + col] = (unsigned short)(h1[nt].y & 0xffffu);
    Hs[(rw + q*4 + 3)*264 + col] = (unsigned short)(h1[nt].y >> 16);
    Hs[(rw + q*4 + 0)*264 + 128 + col] = (unsigned short)(h2[nt].x & 0xffffu);
    Hs[(rw + q*4 + 1)*264 + 128 + col] = (unsigned short)(h2[nt].x >> 16);
    Hs[(rw + q*4 + 2)*264 + 128 + col] = (unsigned short)(h2[nt].y & 0xffffu);
    Hs[(rw + q*4 + 3)*264 + 128 + col] = (unsigned short)(h2[nt].y >> 16);
  }

  __syncthreads();   // barrier7

  // ---- residual + LayerNorm (4 threads per row, 64 cols each) ----
  {
    const int row = t >> 2;
    const int seg = t & 3;
    const float* xrow = xb + row*CH + seg*64;
    float hv[64];
    float sum = 0.f, ss = 0.f;
#pragma unroll
    for (int i = 0; i < 8; i++) {
      short8 hz = *(const short8*)(Hs + row*264 + seg*64 + i*8);
      f32x4 x0 = *(const f32x4*)(xrow + i*8);
      f32x4 x1 = *(const f32x4*)(xrow + i*8 + 4);
#pragma unroll
      for (int j = 0; j < 4; j++) {
        float v0 = x0[j] + bf2f((unsigned short)hz[j]);
        float v1 = x1[j] + bf2f((unsigned short)hz[4 + j]);
        hv[i*8 + j]     = v0;
        hv[i*8 + 4 + j] = v1;
        sum += v0 + v1; ss += v0*v0 + v1*v1;
      }
    }
    sum += __shfl_xor(sum, 1); sum += __shfl_xor(sum, 2);
    ss  += __shfl_xor(ss , 1); ss  += __shfl_xor(ss , 2);
    float mean = sum * (1.f/256.f);
    float var  = ss * (1.f/256.f) - mean*mean;
    float rstd = rsqrtf(var + 1e-5f);
    float* ob = out + (size_t)b * NFQ * CH + row*CH + seg*64;
#pragma unroll
    for (int i = 0; i < 8; i++) {
      f32x4 g0 = *(const f32x4*)(gma + seg*64 + i*8);
      f32x4 g1 = *(const f32x4*)(gma + seg*64 + i*8 + 4);
      f32x4 b0 = *(const f32x4*)(bta + seg*64 + i*8);
      f32x4 b1 = *(const f32x4*)(bta + seg*64 + i*8 + 4);
      f32x4 o0, o1;
#pragma unroll
      for (int j = 0; j < 4; j++) {
        o0[j] = (hv[i*8 + j]     - mean) * rstd * g0[j] + b0[j];
        o1[j] = (hv[i*8 + 4 + j] - mean) * rstd * g1[j] + b1[j];
      }
      *(f32x4*)(ob + i*8)     = o0;
      *(f32x4*)(ob + i*8 + 4) = o1;
    }
  }
}

extern "C" void kernel_launch(void* const* d_in, const int* in_sizes, int n_in,
                              void* d_out, int out_size, void* d_ws, size_t ws_size,
                              hipStream_t stream) {
  const float* x     = (const float*)d_in[0];
  const float* ent   = (const float*)d_in[1];
  const float* adj   = (const float*)d_in[2];
  const float* alpha = (const float*)d_in[3];
  const float* Wq    = (const float*)d_in[4];
  const float* bq    = (const float*)d_in[5];
  const float* Wk    = (const float*)d_in[6];
  const float* bk    = (const float*)d_in[7];
  const float* Wv    = (const float*)d_in[8];
  const float* bv    = (const float*)d_in[9];
  const float* Wg    = (const float*)d_in[10];
  const float* bg    = (const float*)d_in[11];
  const float* gma   = (const float*)d_in[12];
  const float* bta   = (const float*)d_in[13];

  unsigned short* wf    = (unsigned short*)d_ws;                    // 131072 B
  float*          bfull = (float*)((char*)d_ws + 131072);           //   1024 B
  float*          biasf = (float*)((char*)d_ws + 132096);           //  65536 B
  unsigned short* wqb   = (unsigned short*)((char*)d_ws + 197632);  //  65536 B
  unsigned short* wkb   = (unsigned short*)((char*)d_ws + 263168);  //  65536 B

  float* out = (float*)d_out;

  akg_prep<<<260, 256, 0, stream>>>(Wg, Wv, bv, bg, adj, alpha, Wq, Wk,
                                    wf, bfull, biasf, wqb, wkb);
  akg_main<<<2048, 512, 0, stream>>>(x, ent, wqb, bq, wkb, bk, wf, bfull, biasf,
                                     gma, bta, out);
}

// Round 3
// 1070.283 us; speedup vs baseline: 1.0893x; 1.0893x over previous
//
#include <hip/hip_runtime.h>

typedef short short8 __attribute__((ext_vector_type(8)));
typedef float f32x4  __attribute__((ext_vector_type(4)));

#define NFQ 128
#define CH  256

__device__ __forceinline__ unsigned short f2bf(float f) {
  unsigned u = __float_as_uint(f);
  u += 0x7fffu + ((u >> 16) & 1u);
  return (unsigned short)(u >> 16);
}
__device__ __forceinline__ float bf2f(unsigned short h) {
  return __uint_as_float(((unsigned)h) << 16);
}

// prep: wf = bf16(Wg*Wv) [256][256], bfull = Wg*bv + bg (f32), biasf = alpha*relu(adj) (f32),
//       wqb/wkb = bf16(Wq/Wk)
__global__ void akg_prep(const float* __restrict__ Wg,
                         const float* __restrict__ Wv,
                         const float* __restrict__ bv,
                         const float* __restrict__ bg,
                         const float* __restrict__ adj,
                         const float* __restrict__ alpha,
                         const float* __restrict__ Wq,
                         const float* __restrict__ Wk,
                         unsigned short* __restrict__ wf,
                         float* __restrict__ bfull,
                         float* __restrict__ biasf,
                         unsigned short* __restrict__ wqb,
                         unsigned short* __restrict__ wkb) {
  int blk = blockIdx.x, t = threadIdx.x;
  if (blk < 256) {
    float acc = 0.f;
#pragma unroll 8
    for (int j = 0; j < 256; j++)
      acc += Wg[blk*256 + j] * Wv[j*256 + t];   // wf[c][k] = sum_j Wg[c][j] Wv[j][k]
    wf[blk*256 + t] = f2bf(acc);
  } else if (blk == 256) {
    float acc = bg[t];
#pragma unroll 8
    for (int j = 0; j < 256; j++)
      acc += Wg[t*256 + j] * bv[j];
    bfull[t] = acc;
  } else if (blk == 257) {
    float a = alpha[0];
    for (int i = t; i < 128*128; i += 256)
      biasf[i] = a * fmaxf(adj[i], 0.f);
  } else if (blk == 258) {
    for (int i = t; i < 128*256; i += 256) wqb[i] = f2bf(Wq[i]);
  } else {
    for (int i = t; i < 128*256; i += 256) wkb[i] = f2bf(Wk[i]);
  }
}

// LDS = 69,632 B -> 2 blocks/CU. QK first; VW in two 128-col halves after attention,
// each half reusing the dead K region. z-halves packed to bf16 in registers; residual+LN
// done fully in-register (MFMA C-layout gives each lane 4 rows x 16 cols; row-reduce via
// __shfl_xor over the l16 group). No Hs staging, no hv[64] -> no scratch spills at the
// 128-VGPR budget of __launch_bounds__(512,2) (round-0 empirical: (512,4) forced 64 VGPRs
// and 750 MB of spill traffic).
__global__ __launch_bounds__(512, 2) void akg_main(
    const float* __restrict__ x,
    const float* __restrict__ ent,
    const unsigned short* __restrict__ wqb,
    const float* __restrict__ bq,
    const unsigned short* __restrict__ wkb,
    const float* __restrict__ bk,
    const unsigned short* __restrict__ wf,
    const float* __restrict__ bfull,
    const float* __restrict__ biasf,
    const float* __restrict__ gma,
    const float* __restrict__ bta,
    float* __restrict__ out) {
  const int b    = blockIdx.x;
  const int t    = threadIdx.x;
  const int wv   = t >> 6;          // wave 0..7, owns rows [16wv, 16wv+16)
  const int lane = t & 63;
  const int q    = lane >> 4;       // quad
  const int l16  = lane & 15;
  const int rw   = wv * 16;

  __shared__ __align__(16) unsigned short S[34816];   // 69,632 B -> 2 blocks/CU
  unsigned short* Qs = S;           // [128][136] bf16: Q', then attn (wave-private rows)
  unsigned short* Ks = S + 17408;   // [128][136] bf16: K, then VW^T half (128 cols)

  const float* xb = x + (size_t)b * NFQ * CH;
  const int arow = rw + l16;
  const f32x4 zero4 = {0.f, 0.f, 0.f, 0.f};

  // ---- xe = x + ent A-fragments (bf16) for my 16 rows ----
  short8 xf[8];
#pragma unroll
  for (int ks = 0; ks < 8; ks++) {
    f32x4 a0 = *(const f32x4*)(xb + arow*CH + ks*32 + q*8);
    f32x4 a1 = *(const f32x4*)(xb + arow*CH + ks*32 + q*8 + 4);
    f32x4 e0 = *(const f32x4*)(ent + arow*CH + ks*32 + q*8);
    f32x4 e1 = *(const f32x4*)(ent + arow*CH + ks*32 + q*8 + 4);
    short8 s;
#pragma unroll
    for (int j = 0; j < 4; j++) {
      s[j]     = (short)f2bf(a0[j] + e0[j]);
      s[4 + j] = (short)f2bf(a1[j] + e1[j]);
    }
    xf[ks] = s;
  }

  // ---- K = xe*Wk^T + bk -> Ks ----
  f32x4 ac[8];
#pragma unroll
  for (int nt = 0; nt < 8; nt++) ac[nt] = zero4;
#pragma unroll
  for (int ks = 0; ks < 8; ks++) {
#pragma unroll
    for (int nt = 0; nt < 8; nt++) {
      short8 bf = *(const short8*)(wkb + (nt*16 + l16)*CH + ks*32 + q*8);
      ac[nt] = __builtin_amdgcn_mfma_f32_16x16x32_bf16(xf[ks], bf, ac[nt], 0, 0, 0);
    }
  }
#pragma unroll
  for (int nt = 0; nt < 8; nt++) {
    float bb = bk[nt*16 + l16];
#pragma unroll
    for (int r = 0; r < 4; r++)
      Ks[(rw + q*4 + r)*136 + nt*16 + l16] = f2bf(ac[nt][r] + bb);
  }

  // ---- Q' = (xe*Wq^T + bq)/sqrt(128) -> Qs ----
#pragma unroll
  for (int nt = 0; nt < 8; nt++) ac[nt] = zero4;
#pragma unroll
  for (int ks = 0; ks < 8; ks++) {
#pragma unroll
    for (int nt = 0; nt < 8; nt++) {
      short8 bf = *(const short8*)(wqb + (nt*16 + l16)*CH + ks*32 + q*8);
      ac[nt] = __builtin_amdgcn_mfma_f32_16x16x32_bf16(xf[ks], bf, ac[nt], 0, 0, 0);
    }
  }
  const float RS = 0.08838834764831845f;  // 1/sqrt(128)
#pragma unroll
  for (int nt = 0; nt < 8; nt++) {
    float bb = bq[nt*16 + l16];
#pragma unroll
    for (int r = 0; r < 4; r++)
      Qs[(rw + q*4 + r)*136 + nt*16 + l16] = f2bf((ac[nt][r] + bb) * RS);
  }

  __syncthreads();   // barrier1: Ks/Qs visible to all waves

  // ---- scores = Q'*K^T + bias ----
#pragma unroll
  for (int nt = 0; nt < 8; nt++) ac[nt] = zero4;
#pragma unroll
  for (int ks = 0; ks < 4; ks++) {
    short8 af = *(const short8*)(Qs + (rw + l16)*136 + ks*32 + q*8);
#pragma unroll
    for (int nt = 0; nt < 8; nt++) {
      short8 bf = *(const short8*)(Ks + (nt*16 + l16)*136 + ks*32 + q*8);
      ac[nt] = __builtin_amdgcn_mfma_f32_16x16x32_bf16(af, bf, ac[nt], 0, 0, 0);
    }
  }
#pragma unroll
  for (int nt = 0; nt < 8; nt++)
#pragma unroll
    for (int r = 0; r < 4; r++)
      ac[nt][r] += biasf[(rw + q*4 + r)*128 + nt*16 + l16];

  // ---- softmax per row (row = rw+q*4+r; cols spread over 16 lanes x 8 tiles) ----
  float inv[4];
#pragma unroll
  for (int r = 0; r < 4; r++) {
    float mx = -1e30f;
#pragma unroll
    for (int nt = 0; nt < 8; nt++) mx = fmaxf(mx, ac[nt][r]);
    mx = fmaxf(mx, __shfl_xor(mx, 1));
    mx = fmaxf(mx, __shfl_xor(mx, 2));
    mx = fmaxf(mx, __shfl_xor(mx, 4));
    mx = fmaxf(mx, __shfl_xor(mx, 8));
    float s = 0.f;
#pragma unroll
    for (int nt = 0; nt < 8; nt++) {
      float e = __expf(ac[nt][r] - mx);
      ac[nt][r] = e; s += e;
    }
    s += __shfl_xor(s, 1);
    s += __shfl_xor(s, 2);
    s += __shfl_xor(s, 4);
    s += __shfl_xor(s, 8);
    inv[r] = 1.f / s;
  }
  // attn -> Qs (own rows only; per-wave in-order DS makes write-then-read safe)
#pragma unroll
  for (int nt = 0; nt < 8; nt++)
#pragma unroll
    for (int r = 0; r < 4; r++)
      Qs[(rw + q*4 + r)*136 + nt*16 + l16] = f2bf(ac[nt][r] * inv[r]);

  // ---- reload x A-fragments (pure bf16(x) for VW halves; L2-hot) ----
#pragma unroll
  for (int ks = 0; ks < 8; ks++) {
    f32x4 a0 = *(const f32x4*)(xb + arow*CH + ks*32 + q*8);
    f32x4 a1 = *(const f32x4*)(xb + arow*CH + ks*32 + q*8 + 4);
    short8 s;
#pragma unroll
    for (int j = 0; j < 4; j++) {
      s[j]     = (short)f2bf(a0[j]);
      s[4 + j] = (short)f2bf(a1[j]);
    }
    xf[ks] = s;
  }

  __syncthreads();   // barrier2: scores-phase reads of Ks done -> safe to overwrite

  uint2 h1[8], h2[8];   // packed bf16 relu(z): rows rw+q*4+{0..3} (x/y lo/hi), col nt*16+l16 (+128 for h2)

  // ---- VW half 1 (cols 0..127) = x * wf^T (+bfull) -> Ks region, transposed ----
  {
    f32x4 vc[8];
#pragma unroll
    for (int nt = 0; nt < 8; nt++) vc[nt] = zero4;
#pragma unroll
    for (int ks = 0; ks < 8; ks++) {
#pragma unroll
      for (int nt = 0; nt < 8; nt++) {
        short8 bf = *(const short8*)(wf + (nt*16 + l16)*CH + ks*32 + q*8);
        vc[nt] = __builtin_amdgcn_mfma_f32_16x16x32_bf16(xf[ks], bf, vc[nt], 0, 0, 0);
      }
    }
#pragma unroll
    for (int nt = 0; nt < 8; nt++) {
      float bfc = bfull[nt*16 + l16];
      unsigned p0 = (unsigned)f2bf(vc[nt][0] + bfc) | ((unsigned)f2bf(vc[nt][1] + bfc) << 16);
      unsigned p1 = (unsigned)f2bf(vc[nt][2] + bfc) | ((unsigned)f2bf(vc[nt][3] + bfc) << 16);
      uint2 pk; pk.x = p0; pk.y = p1;
      *(uint2*)(Ks + (nt*16 + l16)*136 + rw + q*4) = pk;
    }
  }
  __syncthreads();   // barrier3: Vt half 1 visible

  // ---- z half 1 = attn * VW[:,0:128]; relu+pack to bf16 immediately ----
  {
    f32x4 av[8];
#pragma unroll
    for (int nt = 0; nt < 8; nt++) av[nt] = zero4;
#pragma unroll
    for (int ks = 0; ks < 4; ks++) {
      short8 af = *(const short8*)(Qs + (rw + l16)*136 + ks*32 + q*8);
#pragma unroll
      for (int nt = 0; nt < 8; nt++) {
        short8 bf = *(const short8*)(Ks + (nt*16 + l16)*136 + ks*32 + q*8);
        av[nt] = __builtin_amdgcn_mfma_f32_16x16x32_bf16(af, bf, av[nt], 0, 0, 0);
      }
    }
#pragma unroll
    for (int nt = 0; nt < 8; nt++) {
      h1[nt].x = (unsigned)f2bf(fmaxf(av[nt][0], 0.f)) |
                 ((unsigned)f2bf(fmaxf(av[nt][1], 0.f)) << 16);
      h1[nt].y = (unsigned)f2bf(fmaxf(av[nt][2], 0.f)) |
                 ((unsigned)f2bf(fmaxf(av[nt][3], 0.f)) << 16);
    }
  }
  __syncthreads();   // barrier4: z-h1 reads done -> safe to overwrite Vt half

  // ---- VW half 2 (cols 128..255) -> Ks region ----
  {
    f32x4 vc[8];
#pragma unroll
    for (int nt = 0; nt < 8; nt++) vc[nt] = zero4;
#pragma unroll
    for (int ks = 0; ks < 8; ks++) {
#pragma unroll
      for (int nt = 0; nt < 8; nt++) {
        short8 bf = *(const short8*)(wf + ((nt + 8)*16 + l16)*CH + ks*32 + q*8);
        vc[nt] = __builtin_amdgcn_mfma_f32_16x16x32_bf16(xf[ks], bf, vc[nt], 0, 0, 0);
      }
    }
#pragma unroll
    for (int nt = 0; nt < 8; nt++) {
      float bfc = bfull[(nt + 8)*16 + l16];
      unsigned p0 = (unsigned)f2bf(vc[nt][0] + bfc) | ((unsigned)f2bf(vc[nt][1] + bfc) << 16);
      unsigned p1 = (unsigned)f2bf(vc[nt][2] + bfc) | ((unsigned)f2bf(vc[nt][3] + bfc) << 16);
      uint2 pk; pk.x = p0; pk.y = p1;
      *(uint2*)(Ks + (nt*16 + l16)*136 + rw + q*4) = pk;
    }
  }
  __syncthreads();   // barrier5: Vt half 2 visible

  // ---- z half 2 = attn * VW[:,128:256]; relu+pack to bf16 immediately ----
  {
    f32x4 av[8];
#pragma unroll
    for (int nt = 0; nt < 8; nt++) av[nt] = zero4;
#pragma unroll
    for (int ks = 0; ks < 4; ks++) {
      short8 af = *(const short8*)(Qs + (rw + l16)*136 + ks*32 + q*8);
#pragma unroll
      for (int nt = 0; nt < 8; nt++) {
        short8 bf = *(const short8*)(Ks + (nt*16 + l16)*136 + ks*32 + q*8);
        av[nt] = __builtin_amdgcn_mfma_f32_16x16x32_bf16(af, bf, av[nt], 0, 0, 0);
      }
    }
#pragma unroll
    for (int nt = 0; nt < 8; nt++) {
      h2[nt].x = (unsigned)f2bf(fmaxf(av[nt][0], 0.f)) |
                 ((unsigned)f2bf(fmaxf(av[nt][1], 0.f)) << 16);
      h2[nt].y = (unsigned)f2bf(fmaxf(av[nt][2], 0.f)) |
                 ((unsigned)f2bf(fmaxf(av[nt][3], 0.f)) << 16);
    }
  }

  // ---- residual + LayerNorm fully in-register (no barrier needed) ----
  // Lane holds rows rw+q*4+{0..3}, cols {nt*16+l16, 128+nt*16+l16}. Row-reduce:
  // 16 in-lane adds + shfl_xor(1,2,4,8) across the 16-lane l16 group.
  float gv[16], bv2[16];
#pragma unroll
  for (int nt = 0; nt < 8; nt++) {
    gv[nt]      = gma[nt*16 + l16];
    gv[8 + nt]  = gma[128 + nt*16 + l16];
    bv2[nt]     = bta[nt*16 + l16];
    bv2[8 + nt] = bta[128 + nt*16 + l16];
  }
#pragma unroll
  for (int r = 0; r < 4; r++) {
    const int row = rw + q*4 + r;
    const float* xr = xb + row*CH;
    float v[16];
    float sum = 0.f, ss = 0.f;
#pragma unroll
    for (int nt = 0; nt < 8; nt++) {
      unsigned p1 = (r & 2) ? h1[nt].y : h1[nt].x;
      unsigned p2 = (r & 2) ? h2[nt].y : h2[nt].x;
      unsigned short u1 = (r & 1) ? (unsigned short)(p1 >> 16) : (unsigned short)(p1 & 0xffffu);
      unsigned short u2 = (r & 1) ? (unsigned short)(p2 >> 16) : (unsigned short)(p2 & 0xffffu);
      float v1 = xr[nt*16 + l16]       + bf2f(u1);
      float v2 = xr[128 + nt*16 + l16] + bf2f(u2);
      v[nt]     = v1;
      v[8 + nt] = v2;
      sum += v1 + v2;
      ss  += v1*v1 + v2*v2;
    }
    sum += __shfl_xor(sum, 1); sum += __shfl_xor(sum, 2);
    sum += __shfl_xor(sum, 4); sum += __shfl_xor(sum, 8);
    ss  += __shfl_xor(ss , 1); ss  += __shfl_xor(ss , 2);
    ss  += __shfl_xor(ss , 4); ss  += __shfl_xor(ss , 8);
    float mean = sum * (1.f/256.f);
    float var  = ss * (1.f/256.f) - mean*mean;
    float rstd = rsqrtf(var + 1e-5f);
    float* orow = out + (size_t)b * NFQ * CH + row*CH;
#pragma unroll
    for (int nt = 0; nt < 8; nt++) {
      orow[nt*16 + l16]       = (v[nt]     - mean) * rstd * gv[nt]     + bv2[nt];
      orow[128 + nt*16 + l16] = (v[8 + nt] - mean) * rstd * gv[8 + nt] + bv2[8 + nt];
    }
  }
}

extern "C" void kernel_launch(void* const* d_in, const int* in_sizes, int n_in,
                              void* d_out, int out_size, void* d_ws, size_t ws_size,
                              hipStream_t stream) {
  const float* x     = (const float*)d_in[0];
  const float* ent   = (const float*)d_in[1];
  const float* adj   = (const float*)d_in[2];
  const float* alpha = (const float*)d_in[3];
  const float* Wq    = (const float*)d_in[4];
  const float* bq    = (const float*)d_in[5];
  const float* Wk    = (const float*)d_in[6];
  const float* bk    = (const float*)d_in[7];
  const float* Wv    = (const float*)d_in[8];
  const float* bv    = (const float*)d_in[9];
  const float* Wg    = (const float*)d_in[10];
  const float* bg    = (const float*)d_in[11];
  const float* gma   = (const float*)d_in[12];
  const float* bta   = (const float*)d_in[13];

  unsigned short* wf    = (unsigned short*)d_ws;                    // 131072 B
  float*          bfull = (float*)((char*)d_ws + 131072);           //   1024 B
  float*          biasf = (float*)((char*)d_ws + 132096);           //  65536 B
  unsigned short* wqb   = (unsigned short*)((char*)d_ws + 197632);  //  65536 B
  unsigned short* wkb   = (unsigned short*)((char*)d_ws + 263168);  //  65536 B

  float* out = (float*)d_out;

  akg_prep<<<260, 256, 0, stream>>>(Wg, Wv, bv, bg, adj, alpha, Wq, Wk,
                                    wf, bfull, biasf, wqb, wkb);
  akg_main<<<2048, 512, 0, stream>>>(x, ent, wqb, bq, wkb, bk, wf, bfull, biasf,
                                     gma, bta, out);
}